// Round 1
// baseline (1039.893 us; speedup 1.0000x reference)
//
#include <hip/hip_runtime.h>
#include <stdint.h>

#define IN_F    4096
#define OUT_F   16384
#define ACT_IN  2048
#define ACT_OUT 8192
#define NROWS   8192   // B*S = 4*2048

typedef __bf16 bf16;
typedef __bf16 bf16x8 __attribute__((ext_vector_type(8)));
typedef float  f32x4  __attribute__((ext_vector_type(4)));

// ---- 256x256 tile, BK=32, 8 waves (2M x 4N), 4-deep LDS pipeline ----
#define BM 256
#define BN 256
#define BK 32
#define KSTEPS   (ACT_IN / BK)     // 64
#define ABYTES   (BM * BK * 2)     // 16 KiB A panel
#define BUFBYTES (2 * ABYTES)      // 32 KiB per buffer (A + B)
#define TSTRIDE 34                 // epilogue f32 tile stride
#define CMAX 64                    // output-col chunk width for coverage sweep

// ---- async global->LDS, 16B per lane (dest = wave-uniform base + lane*16) ----
__device__ __forceinline__ void g2lds16(const void* g, void* l) {
  __builtin_amdgcn_global_load_lds(
      (const __attribute__((address_space(1))) void*)(uintptr_t)g,
      (__attribute__((address_space(3))) void*)(uint32_t)(uintptr_t)l,
      16, 0, 0);
}

// counted vmcnt wait (never 0 in steady state) + scheduler fence (rule 18)
#define WAITVM(n) do { asm volatile("s_waitcnt vmcnt(" #n ")" ::: "memory"); \
                       __builtin_amdgcn_sched_barrier(0); } while (0)
// raw barrier WITHOUT the __syncthreads() vmcnt(0) drain — loads stay in flight
#define BARRIER() do { asm volatile("" ::: "memory");                        \
                       __builtin_amdgcn_s_barrier();                         \
                       asm volatile("" ::: "memory"); } while (0)

// ---- gather active input columns, cast f32 -> bf16 ----
__global__ void gather_cast_x(const float* __restrict__ x,
                              const int* __restrict__ in_idx,
                              bf16* __restrict__ A) {
  int n  = blockIdx.x;
  int k0 = threadIdx.x << 3;
  const float* xr = x + (size_t)n * IN_F;
  int4 i0 = *reinterpret_cast<const int4*>(in_idx + k0);
  int4 i1 = *reinterpret_cast<const int4*>(in_idx + k0 + 4);
  bf16x8 v;
  v[0] = (bf16)xr[i0.x]; v[1] = (bf16)xr[i0.y];
  v[2] = (bf16)xr[i0.z]; v[3] = (bf16)xr[i0.w];
  v[4] = (bf16)xr[i1.x]; v[5] = (bf16)xr[i1.y];
  v[6] = (bf16)xr[i1.z]; v[7] = (bf16)xr[i1.w];
  *reinterpret_cast<bf16x8*>(A + (size_t)n * ACT_IN + k0) = v;
}

// ---- cast weight f32 -> bf16 (already N x K row-major = gemm_bt layout) ----
__global__ void cast_w_kernel(const float* __restrict__ w, bf16* __restrict__ W) {
  size_t base = ((size_t)blockIdx.x * blockDim.x + threadIdx.x) * 8;
  float4 f0 = *reinterpret_cast<const float4*>(w + base);
  float4 f1 = *reinterpret_cast<const float4*>(w + base + 4);
  bf16x8 v;
  v[0] = (bf16)f0.x; v[1] = (bf16)f0.y; v[2] = (bf16)f0.z; v[3] = (bf16)f0.w;
  v[4] = (bf16)f1.x; v[5] = (bf16)f1.y; v[6] = (bf16)f1.z; v[7] = (bf16)f1.w;
  *reinterpret_cast<bf16x8*>(W + base) = v;
}

// ---- bf16 GEMM (C = A * W^T), 256^2 tile, deep-pipelined, fused scatter ----
// LDS swizzle (T2): physical byte x within a panel holds logical byte
// x ^ (((x>>8)&3)<<4)  — involution, key bits [9:8] (row>>2) into bits [5:4]
// (k-quad). global_load_lds writes linearly, so the swizzle is applied by
// pre-swizzling the per-lane GLOBAL source k-quad; ds_read applies the same
// XOR. Turns the 8-way b128 read conflict (row stride 64B) into 2-way (free).
__global__ __launch_bounds__(512, 2)
void gemm_scatter(const bf16* __restrict__ A,      // [NROWS][ACT_IN]
                  const bf16* __restrict__ W,      // [ACT_OUT][ACT_IN]
                  const float* __restrict__ bias,  // [ACT_OUT]
                  const int* __restrict__ out_idx, // [ACT_OUT]
                  float* __restrict__ out) {       // [NROWS][OUT_F]
  __shared__ __align__(16) char smraw[4 * BUFBYTES];   // 128 KiB

  const int tid  = threadIdx.x;
  const int lane = tid & 63;
  const int quad = lane >> 4;
  const int l16  = lane & 15;
  const int wave = tid >> 6;
  const int wm   = (wave & 1) << 7;   // 0 / 128  (rows)
  const int wn   = (wave >> 1) << 6;  // 0/64/128/192 (cols)
  const int m0   = blockIdx.y * BM;
  const int n0   = blockIdx.x * BN;
  // NOTE: no XCD swizzle. Default x-fastest dispatch gives each XCD a fixed
  // 4MB W-slice that exactly fits its private L2 (keeps FETCH_SIZE low).

  // ---- staging addressing (2 rounds of 128 rows per panel, 16B/thread) ----
  const int srow = tid >> 2;                       // 0..127
  const int sq   = (tid & 3) ^ ((tid >> 4) & 3);   // inverse-swizzled k-quad
  const bf16* Ag0 = A + (size_t)(m0 + srow) * ACT_IN + sq * 8;
  const bf16* Ag1 = Ag0 + (size_t)128 * ACT_IN;
  const bf16* Bg0 = W + (size_t)(n0 + srow) * ACT_IN + sq * 8;
  const bf16* Bg1 = Bg0 + (size_t)128 * ACT_IN;
  const int dA0 = tid * 16;                        // linear LDS dest (bytes)
  const int dA1 = 8192 + tid * 16;
  const int dB0 = ABYTES + tid * 16;
  const int dB1 = ABYTES + 8192 + tid * 16;

  // ---- fragment read addressing (swizzled; key=(l16>>2)&3 for all i,j) ----
  const int ksw  = (quad ^ ((l16 >> 2) & 3)) << 4;
  const int aoff = (wm + l16) * 64 + ksw;          // + i*1024
  const int boff = ABYTES + (wn + l16) * 64 + ksw; // + j*1024

  f32x4 acc[8][4] = {};

#define ISSUE(s) do {                                                        \
    char* sb_ = smraw + (((s) & 3) * BUFBYTES);                              \
    const size_t ko_ = (size_t)(s) * BK;                                     \
    g2lds16(Ag0 + ko_, sb_ + dA0);                                           \
    g2lds16(Ag1 + ko_, sb_ + dA1);                                           \
    g2lds16(Bg0 + ko_, sb_ + dB0);                                           \
    g2lds16(Bg1 + ko_, sb_ + dB1);                                           \
  } while (0)

  // One barrier per K-step. vmcnt(N) BEFORE the barrier => after the barrier
  // every wave knows every wave's batch-(s+1) LDS writes have landed.
  // ISSUE(s+3) targets buf[(s-1)&3], whose reads finished before the
  // previous barrier (consumed by MFMA => lgkmcnt satisfied) — no WAR race.
#define STEP(s, ISS, VMN) do {                                               \
    const char* sb_ = smraw + (((s) & 3) * BUFBYTES);                        \
    bf16x8 af[8], bfr[4];                                                    \
    _Pragma("unroll") for (int i = 0; i < 8; ++i)                            \
      af[i] = *reinterpret_cast<const bf16x8*>(sb_ + aoff + i * 1024);       \
    _Pragma("unroll") for (int j = 0; j < 4; ++j)                            \
      bfr[j] = *reinterpret_cast<const bf16x8*>(sb_ + boff + j * 1024);      \
    if (ISS) ISSUE((s) + 3);                                                 \
    __builtin_amdgcn_s_setprio(1);                                           \
    _Pragma("unroll") for (int i = 0; i < 8; ++i)                            \
      _Pragma("unroll") for (int j = 0; j < 4; ++j)                          \
        acc[i][j] = __builtin_amdgcn_mfma_f32_16x16x32_bf16(af[i], bfr[j],   \
                                                      acc[i][j], 0, 0, 0);   \
    __builtin_amdgcn_s_setprio(0);                                           \
    WAITVM(VMN);                                                             \
    BARRIER();                                                               \
  } while (0)

  // prologue: 3 K-steps in flight (12 loads/wave)
  ISSUE(0); ISSUE(1); ISSUE(2);
  WAITVM(8);      // batch 0 landed (8 = batches 1,2 still in flight)
  BARRIER();

#pragma unroll 1
  for (int s = 0; s < KSTEPS - 3; ++s) STEP(s, 1, 8);  // steady: vmcnt(8)
  STEP(KSTEPS - 3, 0, 4);
  STEP(KSTEPS - 2, 0, 0);
  STEP(KSTEPS - 1, 0, 0);

  // ---- epilogue: 8 chunks of 32 active cols; stage f32 tile in LDS, then
  // dense coalesced coverage sweep (zeros in gaps). Each block owns the
  // disjoint output range (out_idx[n0-1], out_idx[n0+255]] -> exactly-once. --
  __syncthreads();
  float* tile = (float*)smraw;                        // [256][TSTRIDE]
  int*   cmap = (int*)(smraw + 256 * TSTRIDE * 4);    // [CMAX]

  for (int cc = 0; cc < 8; ++cc) {
    __syncthreads();                       // tile free (prev chunk reads done)
    if ((cc >> 1) == (wave >> 1)) {        // 2 waves own these 32 cols
#pragma unroll
      for (int jj = 0; jj < 2; ++jj) {
        const int j  = ((cc & 1) << 1) + jj;     // C/D col group
        const int cl = (jj << 4) + l16;          // 0..31 within chunk
        const float bv = bias[n0 + wn + j * 16 + l16];
#pragma unroll
        for (int i = 0; i < 8; ++i) {
          const int rb = wm + i * 16 + (quad << 2);
#pragma unroll
          for (int r = 0; r < 4; ++r)
            tile[(rb + r) * TSTRIDE + cl] = acc[i][j][r] + bv;
        }
      }
    }

    const int a0   = n0 + cc * 32;                       // first active idx
    const int lo   = (a0 == 0) ? 0 : out_idx[a0 - 1] + 1;
    const int aend = out_idx[a0 + 31];
    const int hi   = (a0 + 31 == ACT_OUT - 1) ? OUT_F - 1 : aend;

    for (int base = lo; base <= hi; base += CMAX) {
      int wd = hi - base + 1; if (wd > CMAX) wd = CMAX;
      __syncthreads();
      if (tid < CMAX) cmap[tid] = -1;
      __syncthreads();
      if (tid < 32) {
        int rel = out_idx[a0 + tid] - base;
        if (rel >= 0 && rel < CMAX) cmap[rel] = tid;
      }
      __syncthreads();
      const int lc = tid & 63;
      if (lc < wd) {
        const int cm = cmap[lc];
        size_t ob = (size_t)(m0 + wave * 32) * OUT_F + base + lc;
#pragma unroll 4
        for (int r = 0; r < 32; ++r) {
          float v = (cm >= 0) ? tile[(wave * 32 + r) * TSTRIDE + cm] : 0.0f;
          out[ob + (size_t)r * OUT_F] = v;
        }
      }
    }
  }
#undef STEP
#undef ISSUE
}

extern "C" void kernel_launch(void* const* d_in, const int* in_sizes, int n_in,
                              void* d_out, int out_size, void* d_ws, size_t ws_size,
                              hipStream_t stream) {
  const float* x       = (const float*)d_in[0];
  const float* w       = (const float*)d_in[1];
  const float* bias    = (const float*)d_in[2];
  const int*   in_idx  = (const int*)d_in[3];
  const int*   out_idx = (const int*)d_in[4];
  float* out = (float*)d_out;

  bf16* A  = (bf16*)d_ws;                                        // 32 MB
  bf16* Wb = (bf16*)((char*)d_ws + (size_t)NROWS * ACT_IN * 2);  // 32 MB

  gather_cast_x<<<NROWS, 256, 0, stream>>>(x, in_idx, A);
  cast_w_kernel<<<(ACT_OUT * (size_t)ACT_IN / 8) / 256, 256, 0, stream>>>(w, Wb);
  gemm_scatter<<<dim3(ACT_OUT / BN, NROWS / BM), 512, 0, stream>>>(A, Wb, bias, out_idx, out);
}